// Round 1
// baseline (3439.460 us; speedup 1.0000x reference)
//
#include <hip/hip_runtime.h>
#include <hip/hip_bf16.h>

// MixSoftmax: B=4 S=1024 H=1024 K=8 E=512 C=10000
// out[t,c] = sum_k softmax_k(ctx@prior_w^T)[t,k] * softmax_c(tanh(ctx@latent_w^T)[t,k,:] @ dec_w^T)[c]
//
// Pipeline:
//  1. f32->bf16 converts (ctx, latent_w, dec_w [padded to 10112 rows])
//  2. k_priors: per-token K=8 softmax (fp32)
//  3. k_latent: MFMA GEMM [4096x1024]@[4096x1024]^T -> tanh -> bf16 latent [32768x512]
//  4. k_dec_pass1: MFMA GEMM tile -> exp -> atomicAdd row sums Z[32768]
//  5. k_dec_pass2: recompute GEMM -> (prior/Z)*exp -> reduce over k (8 rows) -> out

#define BM 128
#define BN 128
#define BK 64
#define LDK 72   // LDS row pitch (bf16 elems): 144B = 9*16B, breaks bank-conflict stride

typedef __attribute__((ext_vector_type(8))) short bf16x8;
typedef __attribute__((ext_vector_type(4))) float f32x4;

__device__ __forceinline__ unsigned short f2bf(float x) {
  union { float f; unsigned int u; } un; un.f = x;
  unsigned int r = un.u + 0x7FFFu + ((un.u >> 16) & 1u);
  return (unsigned short)(r >> 16);
}

__global__ void k_cvt_bf16(const float4* __restrict__ src, ushort4* __restrict__ dst, int n4) {
  int i = blockIdx.x * blockDim.x + threadIdx.x;
  if (i < n4) {
    float4 v = src[i];
    ushort4 o;
    o.x = f2bf(v.x); o.y = f2bf(v.y); o.z = f2bf(v.z); o.w = f2bf(v.w);
    dst[i] = o;
  }
}

__global__ void k_priors(const float* __restrict__ ctx, const float* __restrict__ pw,
                         const float* __restrict__ pb, float* __restrict__ priors) {
  int t = blockIdx.x;
  int lane = threadIdx.x;  // 64 threads
  __shared__ float logit[8];
  const float* c = ctx + (size_t)t * 1024;
  for (int k = 0; k < 8; ++k) {
    const float* w = pw + k * 1024;
    float s = 0.f;
    for (int h = lane; h < 1024; h += 64) s += c[h] * w[h];
    #pragma unroll
    for (int m = 1; m <= 32; m <<= 1) s += __shfl_xor(s, m);
    if (lane == 0) logit[k] = s + pb[k];
  }
  __syncthreads();
  if (lane == 0) {
    float mx = logit[0];
    for (int k = 1; k < 8; ++k) mx = fmaxf(mx, logit[k]);
    float z = 0.f, e[8];
    for (int k = 0; k < 8; ++k) { e[k] = __expf(logit[k] - mx); z += e[k]; }
    float inv = 1.f / z;
    for (int k = 0; k < 8; ++k) priors[(size_t)t * 8 + k] = e[k] * inv;
  }
}

// Shared GEMM mainloop: C[m,n] = A[m,:] . B[n,:]  (both row-major, K contiguous)
// 128x128 tile, 4 waves in 2x2, each wave 64x64 = 4x4 frags of 16x16, BK=64.
__device__ __forceinline__ void gemm_mainloop(
    const unsigned short* __restrict__ A, const unsigned short* __restrict__ B,
    int lda, int ldb, int m0, int n0, int ktiles,
    unsigned short* lds, f32x4 acc[4][4]) {
  const int tid = threadIdx.x;
  const int lane = tid & 63;
  const int wave = tid >> 6;
  const int wm = wave & 1, wn = wave >> 1;
  const int lrow = lane & 15, lq = lane >> 4;
  unsigned short* ldsA = lds;
  unsigned short* ldsB = lds + BM * LDK;

  for (int kt = 0; kt < ktiles; ++kt) {
    int k0 = kt * BK;
    uint4 ra[4], rb[4];
    #pragma unroll
    for (int p = 0; p < 4; ++p) {
      int chunk = p * 256 + tid;
      int row = chunk >> 3, kc = chunk & 7;
      ra[p] = *(const uint4*)(A + (size_t)(m0 + row) * lda + k0 + kc * 8);
      rb[p] = *(const uint4*)(B + (size_t)(n0 + row) * ldb + k0 + kc * 8);
    }
    __syncthreads();   // previous iter's LDS reads complete
    #pragma unroll
    for (int p = 0; p < 4; ++p) {
      int chunk = p * 256 + tid;
      int row = chunk >> 3, kc = chunk & 7;
      *(uint4*)(ldsA + row * LDK + kc * 8) = ra[p];
      *(uint4*)(ldsB + row * LDK + kc * 8) = rb[p];
    }
    __syncthreads();
    #pragma unroll
    for (int s = 0; s < 2; ++s) {
      bf16x8 af[4], bfr[4];
      #pragma unroll
      for (int f = 0; f < 4; ++f)
        af[f] = *(const bf16x8*)(ldsA + (wm * 64 + f * 16 + lrow) * LDK + (s * 4 + lq) * 8);
      #pragma unroll
      for (int f = 0; f < 4; ++f)
        bfr[f] = *(const bf16x8*)(ldsB + (wn * 64 + f * 16 + lrow) * LDK + (s * 4 + lq) * 8);
      #pragma unroll
      for (int fi = 0; fi < 4; ++fi)
        #pragma unroll
        for (int fj = 0; fj < 4; ++fj)
          acc[fi][fj] = __builtin_amdgcn_mfma_f32_16x16x32_bf16(af[fi], bfr[fj], acc[fi][fj], 0, 0, 0);
    }
  }
}

// Latent: [4096x1024] @ [4096x1024]^T, epilogue tanh(+bias), store bf16
__global__ __launch_bounds__(256, 2)
void k_latent(const unsigned short* __restrict__ ctxb, const unsigned short* __restrict__ lwb,
              const float* __restrict__ lb, unsigned short* __restrict__ latent) {
  __shared__ unsigned short lds[(BM + BN) * LDK];
  f32x4 zero = {0.f, 0.f, 0.f, 0.f};
  f32x4 acc[4][4];
  #pragma unroll
  for (int i = 0; i < 4; ++i)
    #pragma unroll
    for (int j = 0; j < 4; ++j) acc[i][j] = zero;
  int m0 = blockIdx.y * BM, n0 = blockIdx.x * BN;
  gemm_mainloop(ctxb, lwb, 1024, 1024, m0, n0, 1024 / BK, lds, acc);

  const int lane = threadIdx.x & 63, wave = threadIdx.x >> 6;
  const int wm = wave & 1, wn = wave >> 1, lrow = lane & 15, lq = lane >> 4;
  #pragma unroll
  for (int fi = 0; fi < 4; ++fi)
    #pragma unroll
    for (int fj = 0; fj < 4; ++fj) {
      int gcol = n0 + wn * 64 + fj * 16 + lrow;
      float bias = lb[gcol];
      #pragma unroll
      for (int r = 0; r < 4; ++r) {
        int grow = m0 + wm * 64 + fi * 16 + lq * 4 + r;
        float v = tanhf(acc[fi][fj][r] + bias);
        latent[(size_t)grow * 4096 + gcol] = f2bf(v);
      }
    }
}

// Decoder pass 1: logits tile -> exp -> per-row sums -> atomicAdd Z
__global__ __launch_bounds__(256, 2)
void k_dec_pass1(const unsigned short* __restrict__ latb, const unsigned short* __restrict__ dwb,
                 const float* __restrict__ db, float* __restrict__ Z) {
  __shared__ unsigned short lds[(BM + BN) * LDK];
  f32x4 zero = {0.f, 0.f, 0.f, 0.f};
  f32x4 acc[4][4];
  #pragma unroll
  for (int i = 0; i < 4; ++i)
    #pragma unroll
    for (int j = 0; j < 4; ++j) acc[i][j] = zero;
  int m0 = blockIdx.y * BM, n0 = blockIdx.x * BN;
  gemm_mainloop(latb, dwb, 512, 512, m0, n0, 512 / BK, lds, acc);

  const int lane = threadIdx.x & 63, wave = threadIdx.x >> 6;
  const int wm = wave & 1, wn = wave >> 1, lrow = lane & 15, lq = lane >> 4;
  float rowsum[4][4];
  #pragma unroll
  for (int fi = 0; fi < 4; ++fi)
    #pragma unroll
    for (int r = 0; r < 4; ++r) rowsum[fi][r] = 0.f;
  #pragma unroll
  for (int fj = 0; fj < 4; ++fj) {
    int gcol = n0 + wn * 64 + fj * 16 + lrow;
    bool valid = gcol < 10000;
    float bias = valid ? db[gcol] : 0.f;
    #pragma unroll
    for (int fi = 0; fi < 4; ++fi)
      #pragma unroll
      for (int r = 0; r < 4; ++r)
        if (valid) rowsum[fi][r] += __expf(acc[fi][fj][r] + bias);
  }
  #pragma unroll
  for (int fi = 0; fi < 4; ++fi)
    #pragma unroll
    for (int r = 0; r < 4; ++r) {
      float s = rowsum[fi][r];
      s += __shfl_xor(s, 1); s += __shfl_xor(s, 2);
      s += __shfl_xor(s, 4); s += __shfl_xor(s, 8);
      if (lrow == 0) atomicAdd(&Z[m0 + wm * 64 + fi * 16 + lq * 4 + r], s);
    }
}

// Decoder pass 2: recompute logits -> (prior/Z)*exp -> sum 8 k-rows -> out
__global__ __launch_bounds__(256, 2)
void k_dec_pass2(const unsigned short* __restrict__ latb, const unsigned short* __restrict__ dwb,
                 const float* __restrict__ db, const float* __restrict__ priors,
                 const float* __restrict__ Z, float* __restrict__ out) {
  __shared__ unsigned short lds[(BM + BN) * LDK];
  f32x4 zero = {0.f, 0.f, 0.f, 0.f};
  f32x4 acc[4][4];
  #pragma unroll
  for (int i = 0; i < 4; ++i)
    #pragma unroll
    for (int j = 0; j < 4; ++j) acc[i][j] = zero;
  int m0 = blockIdx.y * BM, n0 = blockIdx.x * BN;
  gemm_mainloop(latb, dwb, 512, 512, m0, n0, 512 / BK, lds, acc);

  const int lane = threadIdx.x & 63, wave = threadIdx.x >> 6;
  const int wm = wave & 1, wn = wave >> 1, lrow = lane & 15, lq = lane >> 4;
  #pragma unroll
  for (int fi = 0; fi < 4; ++fi) {
    int rbase = m0 + wm * 64 + fi * 16 + lq * 4;
    float w[4];
    #pragma unroll
    for (int r = 0; r < 4; ++r) w[r] = priors[rbase + r] / Z[rbase + r];
    #pragma unroll
    for (int fj = 0; fj < 4; ++fj) {
      int gcol = n0 + wn * 64 + fj * 16 + lrow;
      bool valid = gcol < 10000;
      float bias = valid ? db[gcol] : 0.f;
      float part = 0.f;
      #pragma unroll
      for (int r = 0; r < 4; ++r) part += w[r] * __expf(acc[fi][fj][r] + bias);
      // rows rbase..rbase+3 are half of token (rbase>>3); other half sits at lane^16
      float tok = part + __shfl_xor(part, 16);
      if (valid && !(lq & 1)) {
        int trow = rbase >> 3;
        out[(size_t)trow * 10000 + gcol] = tok;
      }
    }
  }
}

extern "C" void kernel_launch(void* const* d_in, const int* in_sizes, int n_in,
                              void* d_out, int out_size, void* d_ws, size_t ws_size,
                              hipStream_t stream) {
  const float* ctx = (const float*)d_in[0];  // [4096,1024]
  const float* pw  = (const float*)d_in[1];  // [8,1024]
  const float* pb  = (const float*)d_in[2];  // [8]
  const float* lw  = (const float*)d_in[3];  // [4096,1024]
  const float* lb  = (const float*)d_in[4];  // [4096]
  const float* dw  = (const float*)d_in[5];  // [10000,512]
  const float* db  = (const float*)d_in[6];  // [10000]
  float* out = (float*)d_out;

  char* ws = (char*)d_ws;
  unsigned short* ctxb = (unsigned short*)ws;                // 8,388,608 B
  unsigned short* lwb  = (unsigned short*)(ws + 8388608);    // 8,388,608 B
  unsigned short* dwb  = (unsigned short*)(ws + 16777216);   // 10112*512*2 = 10,354,688 B
  unsigned short* latb = (unsigned short*)(ws + 27131904);   // 32768*512*2 = 33,554,432 B
  float* priors        = (float*)(ws + 60686336);            // 131,072 B
  float* Z             = (float*)(ws + 60817408);            // 131,072 B
  // total 60,948,480 B

  k_cvt_bf16<<<4096, 256, 0, stream>>>((const float4*)ctx, (ushort4*)ctxb, 1048576);
  k_cvt_bf16<<<4096, 256, 0, stream>>>((const float4*)lw,  (ushort4*)lwb,  1048576);
  k_cvt_bf16<<<5000, 256, 0, stream>>>((const float4*)dw,  (ushort4*)dwb,  1280000);
  hipMemsetAsync(dwb + (size_t)10000 * 512, 0, (size_t)112 * 512 * 2, stream);  // zero pad rows
  hipMemsetAsync(Z, 0, 32768 * 4, stream);

  k_priors<<<4096, 64, 0, stream>>>(ctx, pw, pb, priors);
  k_latent<<<dim3(32, 32), 256, 0, stream>>>(ctxb, lwb, lb, latb);
  k_dec_pass1<<<dim3(79, 256), 256, 0, stream>>>(latb, dwb, db, Z);
  k_dec_pass2<<<dim3(79, 256), 256, 0, stream>>>(latb, dwb, db, priors, Z, out);
}

// Round 2
// 3174.536 us; speedup vs baseline: 1.0835x; 1.0835x over previous
//
#include <hip/hip_runtime.h>
#include <hip/hip_bf16.h>

// MixSoftmax: B=4 S=1024 H=1024 K=8 E=512 C=10000
// out[t,c] = sum_k softmax_k(ctx@prior_w^T)[t,k] * softmax_c(tanh(ctx@latent_w^T)[t,k,:] @ dec_w^T)[c]
//
// R2: XCD-aware block swizzle (each XCD owns a 1.31 MB dwb column slice ->
// L2-resident; latb window ~1.7 MB also resident) + LDS-staged coalesced
// float4 epilogue stores (kill partial-line write amplification).

#define BM 128
#define BN 128
#define BK 64
#define LDK 72   // LDS row pitch (bf16 elems): 144B; lane stride 144B -> 2-way bank alias (free)

typedef __attribute__((ext_vector_type(8))) short bf16x8;
typedef __attribute__((ext_vector_type(4))) float f32x4;

__device__ __forceinline__ unsigned short f2bf(float x) {
  union { float f; unsigned int u; } un; un.f = x;
  unsigned int r = un.u + 0x7FFFu + ((un.u >> 16) & 1u);
  return (unsigned short)(r >> 16);
}

__global__ void k_cvt_bf16(const float4* __restrict__ src, ushort4* __restrict__ dst, int n4) {
  int i = blockIdx.x * blockDim.x + threadIdx.x;
  if (i < n4) {
    float4 v = src[i];
    ushort4 o;
    o.x = f2bf(v.x); o.y = f2bf(v.y); o.z = f2bf(v.z); o.w = f2bf(v.w);
    dst[i] = o;
  }
}

__global__ void k_priors(const float* __restrict__ ctx, const float* __restrict__ pw,
                         const float* __restrict__ pb, float* __restrict__ priors) {
  int t = blockIdx.x;
  int lane = threadIdx.x;  // 64 threads
  __shared__ float logit[8];
  const float* c = ctx + (size_t)t * 1024;
  for (int k = 0; k < 8; ++k) {
    const float* w = pw + k * 1024;
    float s = 0.f;
    for (int h = lane; h < 1024; h += 64) s += c[h] * w[h];
    #pragma unroll
    for (int m = 1; m <= 32; m <<= 1) s += __shfl_xor(s, m);
    if (lane == 0) logit[k] = s + pb[k];
  }
  __syncthreads();
  if (lane == 0) {
    float mx = logit[0];
    for (int k = 1; k < 8; ++k) mx = fmaxf(mx, logit[k]);
    float z = 0.f, e[8];
    for (int k = 0; k < 8; ++k) { e[k] = __expf(logit[k] - mx); z += e[k]; }
    float inv = 1.f / z;
    for (int k = 0; k < 8; ++k) priors[(size_t)t * 8 + k] = e[k] * inv;
  }
}

// Shared GEMM mainloop: C[m,n] = A[m,:] . B[n,:]  (both row-major, K contiguous)
// 128x128 tile, 4 waves in 2x2, each wave 64x64 = 4x4 frags of 16x16, BK=64.
__device__ __forceinline__ void gemm_mainloop(
    const unsigned short* __restrict__ A, const unsigned short* __restrict__ B,
    int lda, int ldb, int m0, int n0, int ktiles,
    unsigned short* lds, f32x4 acc[4][4]) {
  const int tid = threadIdx.x;
  const int lane = tid & 63;
  const int wave = tid >> 6;
  const int wm = wave & 1, wn = wave >> 1;
  const int lrow = lane & 15, lq = lane >> 4;
  unsigned short* ldsA = lds;
  unsigned short* ldsB = lds + BM * LDK;

  for (int kt = 0; kt < ktiles; ++kt) {
    int k0 = kt * BK;
    uint4 ra[4], rb[4];
    #pragma unroll
    for (int p = 0; p < 4; ++p) {
      int chunk = p * 256 + tid;
      int row = chunk >> 3, kc = chunk & 7;
      ra[p] = *(const uint4*)(A + (size_t)(m0 + row) * lda + k0 + kc * 8);
      rb[p] = *(const uint4*)(B + (size_t)(n0 + row) * ldb + k0 + kc * 8);
    }
    __syncthreads();   // previous iter's LDS reads complete
    #pragma unroll
    for (int p = 0; p < 4; ++p) {
      int chunk = p * 256 + tid;
      int row = chunk >> 3, kc = chunk & 7;
      *(uint4*)(ldsA + row * LDK + kc * 8) = ra[p];
      *(uint4*)(ldsB + row * LDK + kc * 8) = rb[p];
    }
    __syncthreads();
    #pragma unroll
    for (int s = 0; s < 2; ++s) {
      bf16x8 af[4], bfr[4];
      #pragma unroll
      for (int f = 0; f < 4; ++f)
        af[f] = *(const bf16x8*)(ldsA + (wm * 64 + f * 16 + lrow) * LDK + (s * 4 + lq) * 8);
      #pragma unroll
      for (int f = 0; f < 4; ++f)
        bfr[f] = *(const bf16x8*)(ldsB + (wn * 64 + f * 16 + lrow) * LDK + (s * 4 + lq) * 8);
      #pragma unroll
      for (int fi = 0; fi < 4; ++fi)
        #pragma unroll
        for (int fj = 0; fj < 4; ++fj)
          acc[fi][fj] = __builtin_amdgcn_mfma_f32_16x16x32_bf16(af[fi], bfr[fj], acc[fi][fj], 0, 0, 0);
    }
  }
}

// Latent: [4096x1024] @ [4096x1024]^T, epilogue tanh(+bias), store bf16
// 1024 blocks: xcd-sliced (8 xcd x 4 col-tiles x 32 row-tiles)
__global__ __launch_bounds__(256, 4)
void k_latent(const unsigned short* __restrict__ ctxb, const unsigned short* __restrict__ lwb,
              const float* __restrict__ lb, unsigned short* __restrict__ latent) {
  __shared__ unsigned short lds[(BM + BN) * LDK];
  f32x4 zero = {0.f, 0.f, 0.f, 0.f};
  f32x4 acc[4][4];
  #pragma unroll
  for (int i = 0; i < 4; ++i)
    #pragma unroll
    for (int j = 0; j < 4; ++j) acc[i][j] = zero;
  int l = blockIdx.x;
  int xcd = l & 7, idx = l >> 3;
  int ctl = idx & 3, by = idx >> 2;
  int m0 = by * BM, n0 = (xcd * 4 + ctl) * BN;
  gemm_mainloop(ctxb, lwb, 1024, 1024, m0, n0, 1024 / BK, lds, acc);

  const int lane = threadIdx.x & 63, wave = threadIdx.x >> 6;
  const int wm = wave & 1, wn = wave >> 1, lrow = lane & 15, lq = lane >> 4;
  #pragma unroll
  for (int fi = 0; fi < 4; ++fi)
    #pragma unroll
    for (int fj = 0; fj < 4; ++fj) {
      int gcol = n0 + wn * 64 + fj * 16 + lrow;
      float bias = lb[gcol];
      #pragma unroll
      for (int r = 0; r < 4; ++r) {
        int grow = m0 + wm * 64 + fi * 16 + lq * 4 + r;
        float v = tanhf(acc[fi][fj][r] + bias);
        latent[(size_t)grow * 4096 + gcol] = f2bf(v);
      }
    }
}

// Decoder pass 1: logits tile -> exp -> per-row sums -> atomicAdd Z
// grid: 20480 linear; xcd = l&7 owns col-tiles [xcd*10, xcd*10+10)
__global__ __launch_bounds__(256, 4)
void k_dec_pass1(const unsigned short* __restrict__ latb, const unsigned short* __restrict__ dwb,
                 const float* __restrict__ db, float* __restrict__ Z) {
  __shared__ unsigned short lds[(BM + BN) * LDK];
  int l = blockIdx.x;
  int xcd = l & 7, idx = l >> 3;
  int ctl = idx % 10, by = idx / 10;
  int n0 = (xcd * 10 + ctl) * BN, m0 = by * BM;
  if (n0 >= 10000) return;   // whole-block early exit (pure-pad tile), before any barrier

  f32x4 zero = {0.f, 0.f, 0.f, 0.f};
  f32x4 acc[4][4];
  #pragma unroll
  for (int i = 0; i < 4; ++i)
    #pragma unroll
    for (int j = 0; j < 4; ++j) acc[i][j] = zero;
  gemm_mainloop(latb, dwb, 512, 512, m0, n0, 512 / BK, lds, acc);

  const int lane = threadIdx.x & 63, wave = threadIdx.x >> 6;
  const int wm = wave & 1, wn = wave >> 1, lrow = lane & 15, lq = lane >> 4;
  float rowsum[4][4];
  #pragma unroll
  for (int fi = 0; fi < 4; ++fi)
    #pragma unroll
    for (int r = 0; r < 4; ++r) rowsum[fi][r] = 0.f;
  #pragma unroll
  for (int fj = 0; fj < 4; ++fj) {
    int gcol = n0 + wn * 64 + fj * 16 + lrow;
    bool valid = gcol < 10000;
    float bias = valid ? db[gcol] : 0.f;
    #pragma unroll
    for (int fi = 0; fi < 4; ++fi)
      #pragma unroll
      for (int r = 0; r < 4; ++r)
        if (valid) rowsum[fi][r] += __expf(acc[fi][fj][r] + bias);
  }
  #pragma unroll
  for (int fi = 0; fi < 4; ++fi)
    #pragma unroll
    for (int r = 0; r < 4; ++r) {
      float s = rowsum[fi][r];
      s += __shfl_xor(s, 1); s += __shfl_xor(s, 2);
      s += __shfl_xor(s, 4); s += __shfl_xor(s, 8);
      if (lrow == 0) atomicAdd(&Z[m0 + wm * 64 + fi * 16 + lq * 4 + r], s);
    }
}

// Decoder pass 2: recompute logits -> (prior/Z)*exp -> sum 8 k-rows ->
// stage 16x128 token tile in LDS -> coalesced float4 stores.
__global__ __launch_bounds__(256, 4)
void k_dec_pass2(const unsigned short* __restrict__ latb, const unsigned short* __restrict__ dwb,
                 const float* __restrict__ db, const float* __restrict__ priors,
                 const float* __restrict__ Z, float* __restrict__ out) {
  __shared__ unsigned short lds[(BM + BN) * LDK];
  int l = blockIdx.x;
  int xcd = l & 7, idx = l >> 3;
  int ctl = idx % 10, by = idx / 10;
  int n0 = (xcd * 10 + ctl) * BN, m0 = by * BM;
  if (n0 >= 10000) return;

  f32x4 zero = {0.f, 0.f, 0.f, 0.f};
  f32x4 acc[4][4];
  #pragma unroll
  for (int i = 0; i < 4; ++i)
    #pragma unroll
    for (int j = 0; j < 4; ++j) acc[i][j] = zero;
  gemm_mainloop(latb, dwb, 512, 512, m0, n0, 512 / BK, lds, acc);

  const int tid = threadIdx.x;
  const int lane = tid & 63, wave = tid >> 6;
  const int wm = wave & 1, wn = wave >> 1, lrow = lane & 15, lq = lane >> 4;

  __syncthreads();                    // mainloop LDS reads done in all waves
  float* ldsO = (float*)lds;          // reuse: 16 tokens x 128 cols = 8 KB

  #pragma unroll
  for (int fi = 0; fi < 4; ++fi) {
    int rbase = m0 + wm * 64 + fi * 16 + lq * 4;
    float w[4];
    #pragma unroll
    for (int r = 0; r < 4; ++r) w[r] = priors[rbase + r] / Z[rbase + r];
    #pragma unroll
    for (int fj = 0; fj < 4; ++fj) {
      int gcol = n0 + wn * 64 + fj * 16 + lrow;
      float bias = (gcol < 10000) ? db[gcol] : 0.f;
      float part = 0.f;
      #pragma unroll
      for (int r = 0; r < 4; ++r) part += w[r] * __expf(acc[fi][fj][r] + bias);
      // rows rbase..rbase+3 are k=0..3 of token (rbase>>3); k=4..7 at lane^16
      float tok = part + __shfl_xor(part, 16);
      if (!(lq & 1)) {
        int tl = wm * 8 + fi * 2 + (lq >> 1);     // local token 0..15
        int cl = wn * 64 + fj * 16 + lrow;        // local col 0..127
        ldsO[tl * 128 + cl] = tok;
      }
    }
  }
  __syncthreads();
  int tok0 = m0 >> 3;
  #pragma unroll
  for (int it = 0; it < 2; ++it) {
    int f = it * 256 + tid;           // 0..511 float4 slots
    int tl = f >> 5, c4 = f & 31;
    int col = n0 + c4 * 4;
    if (col < 10000)
      *(float4*)(out + (size_t)(tok0 + tl) * 10000 + col) = *(float4*)(ldsO + tl * 128 + c4 * 4);
  }
}

extern "C" void kernel_launch(void* const* d_in, const int* in_sizes, int n_in,
                              void* d_out, int out_size, void* d_ws, size_t ws_size,
                              hipStream_t stream) {
  const float* ctx = (const float*)d_in[0];  // [4096,1024]
  const float* pw  = (const float*)d_in[1];  // [8,1024]
  const float* pb  = (const float*)d_in[2];  // [8]
  const float* lw  = (const float*)d_in[3];  // [4096,1024]
  const float* lb  = (const float*)d_in[4];  // [4096]
  const float* dw  = (const float*)d_in[5];  // [10000,512]
  const float* db  = (const float*)d_in[6];  // [10000]
  float* out = (float*)d_out;

  char* ws = (char*)d_ws;
  unsigned short* ctxb = (unsigned short*)ws;                // 8,388,608 B
  unsigned short* lwb  = (unsigned short*)(ws + 8388608);    // 8,388,608 B
  unsigned short* dwb  = (unsigned short*)(ws + 16777216);   // 10112*512*2 = 10,354,688 B
  unsigned short* latb = (unsigned short*)(ws + 27131904);   // 32768*512*2 = 33,554,432 B
  float* priors        = (float*)(ws + 60686336);            // 131,072 B
  float* Z             = (float*)(ws + 60817408);            // 131,072 B
  // total 60,948,480 B

  k_cvt_bf16<<<4096, 256, 0, stream>>>((const float4*)ctx, (ushort4*)ctxb, 1048576);
  k_cvt_bf16<<<4096, 256, 0, stream>>>((const float4*)lw,  (ushort4*)lwb,  1048576);
  k_cvt_bf16<<<5000, 256, 0, stream>>>((const float4*)dw,  (ushort4*)dwb,  1280000);
  hipMemsetAsync(dwb + (size_t)10000 * 512, 0, (size_t)112 * 512 * 2, stream);  // zero pad rows
  hipMemsetAsync(Z, 0, 32768 * 4, stream);

  k_priors<<<4096, 64, 0, stream>>>(ctx, pw, pb, priors);
  k_latent<<<1024, 256, 0, stream>>>(ctxb, lwb, lb, latb);
  k_dec_pass1<<<20480, 256, 0, stream>>>(latb, dwb, db, Z);
  k_dec_pass2<<<20480, 256, 0, stream>>>(latb, dwb, db, priors, Z, out);
}